// Round 7
// baseline (47.073 us; speedup 1.0000x reference)
//
#include <hip/hip_runtime.h>
#include <hip/hip_fp16.h>

// DotProductDecoder: out[e] = sigmoid( dot(h[src[e]], h[dst[e]]) ), D=256.
//
// Structure: fp16 slice-major table hs[8][N][32] (3.2MB/slice, per-XCD
// L2-resident; R5 proved residency: FETCH 124->22MB). Round 7: gather is
// latency/issue-bound (~10 TB/s requested vs ~17 TB/s 64B-of-128B-line L2
// ceiling) -> 16-deep MLP: 128-edge batches, 16 direct index loads (no
// shfl distribute), then 16 independent row loads in flight per wave.

typedef _Float16 half2_raw __attribute__((ext_vector_type(2)));

// XCD-affine transpose-convert. Block b handles slice s=b&7: fp32 columns
// [32s,32s+32) of each row = exactly one 128B line per row.
__global__ __launch_bounds__(256) void convert_slice_f16(
    const float* __restrict__ h, __half* __restrict__ hs, int N)
{
    const int s    = blockIdx.x & 7;
    const int lane = threadIdx.x & 63;
    const int r4   = lane >> 4;       // row 0..3 within wave-quad
    const int c    = lane & 15;       // float2 column within slice
    const int wave = (blockIdx.x >> 3) * (blockDim.x >> 6) + (threadIdx.x >> 6);
    const int nw   = (gridDim.x >> 3) * (blockDim.x >> 6);

    for (int n0 = wave * 4; n0 < N; n0 += nw * 4) {
        const int n = n0 + r4;
        if (n < N) {
            float2 v = *reinterpret_cast<const float2*>(
                h + (size_t)n * 256 + s * 32 + c * 2);
            __half2 p = __floats2half2_rn(v.x, v.y);
            *reinterpret_cast<__half2*>(
                hs + ((size_t)s * N + n) * 32 + c * 2) = p;
        }
    }
}

__device__ inline float dot8_f16(const uint4& v, const uint4& w) {
    float acc = 0.0f;
#if __has_builtin(__builtin_amdgcn_fdot2)
    const half2_raw* pa = reinterpret_cast<const half2_raw*>(&v);
    const half2_raw* pb = reinterpret_cast<const half2_raw*>(&w);
    #pragma unroll
    for (int q = 0; q < 4; ++q)
        acc = __builtin_amdgcn_fdot2(pa[q], pb[q], acc, false);
#else
    const __half2* pa = reinterpret_cast<const __half2*>(&v);
    const __half2* pb = reinterpret_cast<const __half2*>(&w);
    #pragma unroll
    for (int q = 0; q < 4; ++q) {
        float2 fa = __half22float2(pa[q]);
        float2 fb = __half22float2(pb[q]);
        acc += fa.x * fb.x + fa.y * fb.y;
    }
#endif
    return acc;
}

// 4 lanes/edge (q = lane&3 -> 16B chunk, g = lane>>2 -> edge within group).
// 128-edge batches: 16 index loads issued first, then 16 independent
// row loads (src+dst x 8 sub-batches) in flight, then dot + quad reduce.
__global__ __launch_bounds__(256, 4) void slice_gather_dot(
    const __half* __restrict__ hs,      // [8][N][32]
    const int*    __restrict__ src_idx,
    const int*    __restrict__ dst_idx,
    float*        __restrict__ partial, // [8][E]
    int E, int N)
{
    const int slice = blockIdx.x & 7;
    const int lane  = threadIdx.x & 63;
    const int q     = lane & 3;
    const int g     = lane >> 2;
    const int wsl   = (blockIdx.x >> 3) * (blockDim.x >> 6) + (threadIdx.x >> 6);
    const int nwsl  = (gridDim.x >> 3) * (blockDim.x >> 6);

    const __half* hsl = hs + (size_t)slice * N * 32;
    float* psl = partial + (size_t)slice * E;

    const int step = nwsl * 128;
    for (int base = wsl * 128; base < E; base += step) {
        int si[8], di[8];
        #pragma unroll
        for (int sb = 0; sb < 8; ++sb) {
            const int e  = base + sb * 16 + g;
            const int ec = e < E ? e : E - 1;
            si[sb] = src_idx[ec];
            di[sb] = dst_idx[ec];
        }

        uint4 va[8], vb[8];
        #pragma unroll
        for (int sb = 0; sb < 8; ++sb) {
            va[sb] = *reinterpret_cast<const uint4*>(
                hsl + (size_t)si[sb] * 32 + q * 8);
            vb[sb] = *reinterpret_cast<const uint4*>(
                hsl + (size_t)di[sb] * 32 + q * 8);
        }

        #pragma unroll
        for (int sb = 0; sb < 8; ++sb) {
            float acc = dot8_f16(va[sb], vb[sb]);
            acc += __shfl_xor(acc, 1, 4);
            acc += __shfl_xor(acc, 2, 4);
            const int e = base + sb * 16 + g;
            if (q == 0 && e < E)
                __builtin_nontemporal_store(acc, psl + e);
        }
    }
}

__global__ __launch_bounds__(256) void reduce_sigmoid(
    const float* __restrict__ partial, float* __restrict__ out, int E)
{
    int t = blockIdx.x * blockDim.x + threadIdx.x;
    const int stride = gridDim.x * blockDim.x;
    for (; t < E; t += stride) {
        float s = 0.0f;
        #pragma unroll
        for (int k = 0; k < 8; ++k)
            s += __builtin_nontemporal_load(partial + (size_t)k * E + t);
        out[t] = 1.0f / (1.0f + __expf(-s));
    }
}

// ---- Fallbacks ----
__global__ __launch_bounds__(256) void convert_f32_to_f16(
    const float* __restrict__ h, __half* __restrict__ hh, int n8)
{
    int i = blockIdx.x * blockDim.x + threadIdx.x;
    const int stride = gridDim.x * blockDim.x;
    for (; i < n8; i += stride) {
        float4 a = reinterpret_cast<const float4*>(h)[2 * i + 0];
        float4 b = reinterpret_cast<const float4*>(h)[2 * i + 1];
        __half2 p[4];
        p[0] = __floats2half2_rn(a.x, a.y);
        p[1] = __floats2half2_rn(a.z, a.w);
        p[2] = __floats2half2_rn(b.x, b.y);
        p[3] = __floats2half2_rn(b.z, b.w);
        reinterpret_cast<uint4*>(hh)[i] = *reinterpret_cast<uint4*>(p);
    }
}

__global__ __launch_bounds__(256) void gather_dot_f16(
    const __half* __restrict__ hh,
    const int*    __restrict__ src_idx,
    const int*    __restrict__ dst_idx,
    float*        __restrict__ out,
    int E)
{
    const int lane   = threadIdx.x & 63;
    const int wave   = (blockIdx.x * blockDim.x + threadIdx.x) >> 6;
    const int nwaves = (gridDim.x * blockDim.x) >> 6;
    for (int e = wave; e < E; e += nwaves) {
        const int s = src_idx[e];
        const int d = dst_idx[e];
        uint2 ua = *reinterpret_cast<const uint2*>(hh + (size_t)s * 256 + lane * 4);
        uint2 ub = *reinterpret_cast<const uint2*>(hh + (size_t)d * 256 + lane * 4);
        float2 a0 = __half22float2(*reinterpret_cast<__half2*>(&ua.x));
        float2 a1 = __half22float2(*reinterpret_cast<__half2*>(&ua.y));
        float2 b0 = __half22float2(*reinterpret_cast<__half2*>(&ub.x));
        float2 b1 = __half22float2(*reinterpret_cast<__half2*>(&ub.y));
        float acc = a0.x * b0.x + a0.y * b0.y + a1.x * b1.x + a1.y * b1.y;
        #pragma unroll
        for (int off = 32; off >= 1; off >>= 1)
            acc += __shfl_xor(acc, off, 64);
        if (lane == 0) out[e] = 1.0f / (1.0f + __expf(-acc));
    }
}

__global__ __launch_bounds__(256) void gather_dot_f32(
    const float* __restrict__ h,
    const int*   __restrict__ src_idx,
    const int*   __restrict__ dst_idx,
    float*       __restrict__ out,
    int E)
{
    const int lane   = threadIdx.x & 63;
    const int wave   = (blockIdx.x * blockDim.x + threadIdx.x) >> 6;
    const int nwaves = (gridDim.x * blockDim.x) >> 6;
    for (int e = wave; e < E; e += nwaves) {
        const int s = src_idx[e];
        const int d = dst_idx[e];
        const float4 a = *reinterpret_cast<const float4*>(h + (size_t)s * 256 + lane * 4);
        const float4 b = *reinterpret_cast<const float4*>(h + (size_t)d * 256 + lane * 4);
        float acc = a.x * b.x + a.y * b.y + a.z * b.z + a.w * b.w;
        #pragma unroll
        for (int off = 32; off >= 1; off >>= 1)
            acc += __shfl_xor(acc, off, 64);
        if (lane == 0) out[e] = 1.0f / (1.0f + __expf(-acc));
    }
}

extern "C" void kernel_launch(void* const* d_in, const int* in_sizes, int n_in,
                              void* d_out, int out_size, void* d_ws, size_t ws_size,
                              hipStream_t stream) {
    const float* h   = (const float*)d_in[0];
    const int*   ei  = (const int*)d_in[1];   // [2, E]: src row then dst row
    float*       out = (float*)d_out;

    const int ND = in_sizes[0];               // N * 256
    const int N  = ND / 256;
    const int E  = in_sizes[1] / 2;
    const int* src = ei;
    const int* dst = ei + E;

    const size_t tbl_bytes  = (size_t)ND * sizeof(__half);
    const size_t part_bytes = (size_t)8 * E * sizeof(float);

    if (ws_size >= tbl_bytes + part_bytes) {
        __half* hs      = (__half*)d_ws;
        float*  partial = (float*)((char*)d_ws + tbl_bytes);
        convert_slice_f16<<<2048, 256, 0, stream>>>(h, hs, N);
        slice_gather_dot<<<2048, 256, 0, stream>>>(hs, src, dst, partial, E, N);
        reduce_sigmoid<<<1024, 256, 0, stream>>>(partial, out, E);
    } else if (ws_size >= tbl_bytes) {
        __half* hh = (__half*)d_ws;
        convert_f32_to_f16<<<2048, 256, 0, stream>>>(h, hh, ND / 8);
        gather_dot_f16<<<2048, 256, 0, stream>>>(hh, src, dst, out, E);
    } else {
        gather_dot_f32<<<2048, 256, 0, stream>>>(h, src, dst, out, E);
    }
}